// Round 5
// baseline (5672.471 us; speedup 1.0000x reference)
//
#include <hip/hip_runtime.h>

#define HH 80
#define WW 80
#define NPIX 6400
#define CFE 64
#define CMA 3
#define KF 576

typedef unsigned long long u64;
typedef unsigned int u32;

__device__ __forceinline__ void gload4(const float* g, float* l) {
    __builtin_amdgcn_global_load_lds((const __attribute__((address_space(1))) void*)g,
                                     (__attribute__((address_space(3))) void*)l, 4, 0, 0);
}

// ---------------------------------------------------------------------------
// per-pixel channel sum-of-squares (style side only)
// ---------------------------------------------------------------------------
__global__ __launch_bounds__(256)
void pixsq_kernel(const float* __restrict__ sf, const float* __restrict__ sm,
                  float* __restrict__ psf, float* __restrict__ psm) {
    int g = blockIdx.x * 256 + threadIdx.x;
    if (g >= 2 * NPIX) return;
    int b = g / NPIX, m = g - b * NPIX;
    const float* p = sf + (size_t)b * CFE * NPIX + m;
    float a = 0.f;
    #pragma unroll 8
    for (int c = 0; c < CFE; ++c) { float v = p[c * NPIX]; a = fmaf(v, v, a); }
    const float* q = sm + (size_t)b * CMA * NPIX + m;
    float am = 0.f;
    #pragma unroll
    for (int c = 0; c < CMA; ++c) { float v = q[c * NPIX]; am = fmaf(v, v, am); }
    psf[g] = a; psm[g] = am;
}

// 9-tap masked patch-norms -> combined reciprocal rn2 = 1/(||f||*||m||)
__global__ __launch_bounds__(256)
void rn2_kernel(const float* __restrict__ psf, const float* __restrict__ psm,
                float* __restrict__ rn2) {
    int g = blockIdx.x * 256 + threadIdx.x;
    if (g >= 2 * NPIX) return;
    int b = g / NPIX, m = g - b * NPIX;
    int mh = m / WW, mw = m - mh * WW;
    float sF = 0.f, sM = 0.f;
    #pragma unroll
    for (int di = -1; di <= 1; ++di) {
        if ((unsigned)(mh + di) >= HH) continue;
        #pragma unroll
        for (int dj = -1; dj <= 1; ++dj) {
            if ((unsigned)(mw + dj) >= WW) continue;
            int mm = m + di * WW + dj;
            sF += psf[b * NPIX + mm];
            sM += psm[b * NPIX + mm];
        }
    }
    float rf = 1.f / fmaxf(sqrtf(sF), 1e-12f);
    float rm = 1.f / fmaxf(sqrtf(sM), 1e-12f);
    rn2[g] = rf * rm;
}

// ---------------------------------------------------------------------------
// Pass 1: pixel-dot GEMM tile (linear coords) + transpose epilogue writing
// d-major strips Sd[dl][p], dl = (m-n) - dlo.
// ---------------------------------------------------------------------------
__global__ __launch_bounds__(256, 3)
void s0d_kernel(const float* __restrict__ cf, const float* __restrict__ sf,
                const float* __restrict__ cm, const float* __restrict__ smk,
                float* __restrict__ SdF, float* __restrict__ SdM,
                int dlo, int DW, int b) {
    __shared__ __align__(16) float pool[8960];
    float (*As)[128] = (float(*)[128])pool;            // 32x128
    float (*Bs)[128] = (float(*)[128])(pool + 4096);   // 32x128
    float* Amr = pool + 8192;                          // 3x128
    float* Bmr = pool + 8576;                          // 3x128
    float (*T)[129]  = (float(*)[129])pool;            // 64x129 (aliases As/Bs/Amr)

    const int x  = blockIdx.x;
    const int n0 = blockIdx.y << 7;
    const int mt = n0 + dlo + (x << 7);                // m-tile base (may be <0)
    if (mt >= NPIX || mt + 128 <= 0) return;

    const int tid = threadIdx.x;
    const int ty = tid >> 4, tx = tid & 15;
    const int wv = tid >> 6, ln = tid & 63;

    const float* __restrict__ cfb = cf + (size_t)b * CFE * NPIX;
    const float* __restrict__ sfb = sf + (size_t)b * CFE * NPIX;

    if (tid < 128) {
        int p = tid;
        int mm = mt + p; mm = mm < 0 ? 0 : (mm > NPIX - 1 ? NPIX - 1 : mm);
        const float* cmb = cm  + (size_t)b * CMA * NPIX;
        const float* smb = smk + (size_t)b * CMA * NPIX;
        #pragma unroll
        for (int c = 0; c < 3; ++c) {
            Amr[c * 128 + p] = cmb[c * NPIX + n0 + p];
            Bmr[c * 128 + p] = smb[c * NPIX + mm];
        }
    }

    float accF[8][8];
    #pragma unroll
    for (int i = 0; i < 8; ++i)
        #pragma unroll
        for (int j = 0; j < 8; ++j) accF[i][j] = 0.f;

    int mB0 = mt + ln;      mB0 = mB0 < 0 ? 0 : (mB0 > NPIX - 1 ? NPIX - 1 : mB0);
    int mB1 = mt + ln + 64; mB1 = mB1 < 0 ? 0 : (mB1 > NPIX - 1 ? NPIX - 1 : mB1);

    #pragma unroll 1
    for (int half = 0; half < 2; ++half) {
        __syncthreads();
        const int c0 = half * 32 + 8 * wv;
        {
            const float* g = cfb + (size_t)c0 * NPIX + (n0 + ln);
            float* dst = &As[8 * wv][0];
            #pragma unroll
            for (int r = 0; r < 8; ++r) { gload4(g, dst); g += NPIX; dst += 128; }
            g = cfb + (size_t)c0 * NPIX + (n0 + ln + 64);
            dst = &As[8 * wv][64];
            #pragma unroll
            for (int r = 0; r < 8; ++r) { gload4(g, dst); g += NPIX; dst += 128; }
            g = sfb + (size_t)c0 * NPIX + mB0;
            dst = &Bs[8 * wv][0];
            #pragma unroll
            for (int r = 0; r < 8; ++r) { gload4(g, dst); g += NPIX; dst += 128; }
            g = sfb + (size_t)c0 * NPIX + mB1;
            dst = &Bs[8 * wv][64];
            #pragma unroll
            for (int r = 0; r < 8; ++r) { gload4(g, dst); g += NPIX; dst += 128; }
        }
        __syncthreads();
        #pragma unroll 4
        for (int k = 0; k < 32; ++k) {
            float a[8], bb[8];
            *(float4*)&a[0]  = *(const float4*)&As[k][ty * 4];
            *(float4*)&a[4]  = *(const float4*)&As[k][64 + ty * 4];
            *(float4*)&bb[0] = *(const float4*)&Bs[k][tx * 4];
            *(float4*)&bb[4] = *(const float4*)&Bs[k][64 + tx * 4];
            #pragma unroll
            for (int i = 0; i < 8; ++i)
                #pragma unroll
                for (int j = 0; j < 8; ++j)
                    accF[i][j] = fmaf(a[i], bb[j], accF[i][j]);
        }
    }

    float accM[8][8];
    #pragma unroll
    for (int i = 0; i < 8; ++i)
        #pragma unroll
        for (int j = 0; j < 8; ++j) accM[i][j] = 0.f;
    #pragma unroll
    for (int k = 0; k < 3; ++k) {
        float a[8], bb[8];
        *(float4*)&a[0]  = *(const float4*)&Amr[k * 128 + ty * 4];
        *(float4*)&a[4]  = *(const float4*)&Amr[k * 128 + 64 + ty * 4];
        *(float4*)&bb[0] = *(const float4*)&Bmr[k * 128 + tx * 4];
        *(float4*)&bb[4] = *(const float4*)&Bmr[k * 128 + 64 + tx * 4];
        #pragma unroll
        for (int i = 0; i < 8; ++i)
            #pragma unroll
            for (int j = 0; j < 8; ++j)
                accM[i][j] = fmaf(a[i], bb[j], accM[i][j]);
    }

    // transpose epilogue: 4 quarters of 64 diagonals each, via T, then
    // coalesced row writes Sd[dl][n0..n0+128)
    auto epi = [&](float (&acc)[8][8], float* __restrict__ Sd) {
        #pragma unroll 1
        for (int q = 0; q < 4; ++q) {
            const int qdlo = (x << 7) - 128 + (q << 6);
            __syncthreads();
            #pragma unroll
            for (int i = 0; i < 8; ++i) {
                int ri = (i < 4) ? (ty * 4 + i) : (64 + ty * 4 + (i - 4));
                #pragma unroll
                for (int j = 0; j < 8; ++j) {
                    int cj = (j < 4) ? (tx * 4 + j) : (64 + tx * 4 + (j - 4));
                    int t = cj - ri + 128 - (q << 6);
                    if ((unsigned)t < 64u) T[t][ri] = acc[i][j];
                }
            }
            __syncthreads();
            #pragma unroll 1
            for (int e = tid; e < 64 * 128; e += 256) {
                int r = e >> 7, c = e & 127;
                int dl_w = qdlo + r;
                if ((unsigned)dl_w >= (unsigned)DW) continue;
                int cj = c + dl_w - (x << 7);
                if ((unsigned)cj >= 128u) continue;
                int m = mt + cj;
                if ((unsigned)m >= (unsigned)NPIX) continue;
                Sd[(size_t)dl_w * NPIX + n0 + c] = T[r][c];
            }
        }
    };
    epi(accF, SdF);
    epi(accM, SdM);
}

// ---------------------------------------------------------------------------
// Pass 2: 1-D 9-tap stencil along p (d-chunk of 16), score + atomicMax argmax.
// Thread: tp in [0,64) owns rows p0+tp+64i (i=0..7), td in [0,4) owns 4 d cols.
// ---------------------------------------------------------------------------
__global__ __launch_bounds__(256, 2)
void tap2_kernel(const float* __restrict__ SdF, const float* __restrict__ SdM,
                 const float* __restrict__ rn2, u64* __restrict__ pbest,
                 int dlo, int DW, int b) {
    __shared__ __align__(16) float L[674][20];   // (512+162) x 16, stride 20

    const int tid = threadIdx.x;
    const int dl0 = blockIdx.y << 4;
    const int d0  = dlo + dl0;
    const int p0  = blockIdx.x << 9;

    const int pvlo = max(0, -(d0 + 15));
    const int pvhi = min(NPIX, NPIX - d0);
    if (p0 >= pvhi || p0 + 512 <= pvlo) return;

    const int tp = (tid & 15) | ((tid >> 2) & 48);   // (tid&15) + 16*(tid>>6)
    const int td = (tid >> 4) & 3;

    // geometry + per-tap masks (bit i*4+j)
    int pR[8]; bool pv[8];
    u32 tapm[9] = {0, 0, 0, 0, 0, 0, 0, 0, 0};
    #pragma unroll
    for (int i = 0; i < 8; ++i) {
        pR[i] = p0 + tp + (i << 6);
        pv[i] = pR[i] < NPIX;
        if (!pv[i]) continue;
        int ph = pR[i] / 80, pw = pR[i] - ph * 80;
        int hA[3] = {ph >= 1, 1, ph <= 78};
        int wA[3] = {pw >= 1, 1, pw <= 78};
        #pragma unroll
        for (int j = 0; j < 4; ++j) {
            int m = pR[i] + d0 + (td << 2) + j;
            if ((unsigned)m >= NPIX) continue;
            int mh = m / 80, mw = m - mh * 80;
            int hB[3] = {mh >= 1, 1, mh <= 78};
            int wB[3] = {mw >= 1, 1, mw <= 78};
            u32 bit = 1u << (i * 4 + j);
            #pragma unroll
            for (int t9 = 0; t9 < 9; ++t9) {
                int di1 = t9 / 3, dj1 = t9 - (t9 / 3) * 3;
                if (hA[di1] & wA[dj1] & hB[di1] & wB[dj1]) tapm[t9] |= bit;
            }
        }
    }

    auto stage = [&](const float* __restrict__ S) {
        #pragma unroll 1
        for (int e = tid; e < 674 * 16; e += 256) {
            int dl = e / 674;
            int pl = e - dl * 674;
            int ps = p0 - 81 + pl;
            ps = ps < 0 ? 0 : (ps > NPIX - 1 ? NPIX - 1 : ps);
            L[pl][dl] = S[(size_t)(dl0 + dl) * NPIX + ps];
        }
    };

    const int dlt[9] = {-81, -80, -79, -1, 0, 1, 79, 80, 81};

    float pdF[8][4], pdM[8][4];
    #pragma unroll
    for (int i = 0; i < 8; ++i)
        #pragma unroll
        for (int j = 0; j < 4; ++j) { pdF[i][j] = 0.f; pdM[i][j] = 0.f; }

    auto taps = [&](float (&pd)[8][4]) {
        #pragma unroll
        for (int i = 0; i < 8; ++i) {
            const int plb = tp + (i << 6) + 81;
            #pragma unroll
            for (int t9 = 0; t9 < 9; ++t9) {
                const float4 v = *(const float4*)&L[plb + dlt[t9]][td << 2];
                const u32 mk = tapm[t9] >> (i * 4);
                pd[i][0] += (mk & 1) ? v.x : 0.f;
                pd[i][1] += (mk & 2) ? v.y : 0.f;
                pd[i][2] += (mk & 4) ? v.z : 0.f;
                pd[i][3] += (mk & 8) ? v.w : 0.f;
            }
        }
    };

    stage(SdF); __syncthreads(); taps(pdF);
    __syncthreads();
    stage(SdM); __syncthreads(); taps(pdM);

    // score + per-row argmax via sortable key + atomicMax
    const float* __restrict__ rb = rn2 + b * NPIX;
    #pragma unroll
    for (int i = 0; i < 8; ++i) {
        if (!pv[i]) continue;
        u64 key = 0;
        #pragma unroll
        for (int j = 0; j < 4; ++j) {
            int m = pR[i] + d0 + (td << 2) + j;
            if ((unsigned)m >= NPIX) continue;
            float s = pdF[i][j] * pdM[i][j] * rb[m];
            s += 0.f;                                  // -0 -> +0
            u32 u = __float_as_uint(s);
            u ^= (u >> 31) ? 0xFFFFFFFFu : 0x80000000u;
            u64 k = ((u64)u << 32) | (u32)(~(u32)m);
            if (k > key) key = k;
        }
        u64 o = __shfl_xor(key, 16); if (o > key) key = o;
        o = __shfl_xor(key, 32);     if (o > key) key = o;
        if (td == 0 && key)
            atomicMax(&pbest[(size_t)b * NPIX + pR[i]], key);
    }
}

// ---------------------------------------------------------------------------
// Gather the winning style patch per n.
// ---------------------------------------------------------------------------
__global__ __launch_bounds__(64)
void gather_kernel(const float* __restrict__ sf, const u64* __restrict__ pbest,
                   float* __restrict__ out) {
    int n = blockIdx.x, b = blockIdx.y;
    int lane = threadIdx.x;

    u64 key = pbest[(size_t)b * NPIX + n];
    int m = (int)(~(u32)key);
    int mh = m / WW, mw = m - mh * WW;
    const float* sfb = sf + (size_t)b * CFE * NPIX;
    float* ob = out + ((size_t)b * NPIX + n) * (size_t)KF;
    #pragma unroll
    for (int e = lane; e < KF; e += 64) {
        int c = e / 9, pos = e - c * 9;
        int di = pos / 3 - 1, dj = pos - (pos / 3) * 3 - 1;
        int h = mh + di, w = mw + dj;
        ob[e] = ((unsigned)h < HH && (unsigned)w < WW) ? sfb[c * NPIX + h * WW + w] : 0.f;
    }
}

// ---------------------------------------------------------------------------
extern "C" void kernel_launch(void* const* d_in, const int* in_sizes, int n_in,
                              void* d_out, int out_size, void* d_ws, size_t ws_size,
                              hipStream_t stream) {
    const float* cf = (const float*)d_in[0];
    const float* sf = (const float*)d_in[1];
    const float* cm = (const float*)d_in[2];
    const float* sm = (const float*)d_in[3];
    float* out = (float*)d_out;

    float* psf  = (float*)d_ws;
    float* psm  = psf + 2 * NPIX;
    float* rn2  = psm + 2 * NPIX;
    u64*   pbest = (u64*)(rn2 + 2 * NPIX);
    float* Sd   = (float*)(pbest + 2 * NPIX);
    const size_t head_bytes = (size_t)(6 * NPIX) * 4 + (size_t)(2 * NPIX) * 8;

    // strip-width ladder over d
    static const int cfgDW[4] = {1536, 1024, 512, 256};
    int DW = 256;
    for (int k = 0; k < 4; ++k) {
        size_t need = head_bytes + (size_t)2 * cfgDW[k] * NPIX * 4;
        if (need <= ws_size) { DW = cfgDW[k]; break; }
    }
    float* SdF = Sd;
    float* SdM = Sd + (size_t)DW * NPIX;

    hipMemsetAsync(pbest, 0, (size_t)2 * NPIX * 8, stream);
    pixsq_kernel<<<(2 * NPIX + 255) / 256, 256, 0, stream>>>(sf, sm, psf, psm);
    rn2_kernel  <<<(2 * NPIX + 255) / 256, 256, 0, stream>>>(psf, psm, rn2);

    const int nstrip = (2 * NPIX + DW - 1) / DW;
    for (int s = 0; s < nstrip; ++s) {
        int dlo = -NPIX + s * DW;
        for (int bb = 0; bb < 2; ++bb) {
            s0d_kernel<<<dim3(DW / 128 + 1, NPIX / 128, 1), 256, 0, stream>>>(
                cf, sf, cm, sm, SdF, SdM, dlo, DW, bb);
            tap2_kernel<<<dim3((NPIX + 511) / 512, DW / 16, 1), 256, 0, stream>>>(
                SdF, SdM, rn2, pbest, dlo, DW, bb);
        }
    }
    gather_kernel<<<dim3(NPIX, 2), 64, 0, stream>>>(sf, pbest, out);
}

// Round 6
// 993.042 us; speedup vs baseline: 5.7122x; 5.7122x over previous
//
#include <hip/hip_runtime.h>

#define HH 80
#define WW 80
#define NPIX 6400
#define PW 82
#define NPP (PW*PW)        // 6724 padded pixels
#define CFE 64
#define CMA 3
#define KF 576
#define GUARD 768
#define NREG 8

typedef unsigned long long u64;
typedef unsigned int u32;

__device__ __forceinline__ void gload4(const float* g, float* l) {
    __builtin_amdgcn_global_load_lds((const __attribute__((address_space(1))) void*)g,
                                     (__attribute__((address_space(3))) void*)l, 4, 0, 0);
}
__device__ __forceinline__ float4 ld4(const float* p) { return *(const float4*)p; }

// ---------------------------------------------------------------------------
// per-pixel channel sum-of-squares (style side only), real grid
// ---------------------------------------------------------------------------
__global__ __launch_bounds__(256)
void pixsq_kernel(const float* __restrict__ sf, const float* __restrict__ sm,
                  float* __restrict__ psf, float* __restrict__ psm) {
    int g = blockIdx.x * 256 + threadIdx.x;
    if (g >= 2 * NPIX) return;
    int b = g / NPIX, m = g - b * NPIX;
    const float* p = sf + (size_t)b * CFE * NPIX + m;
    float a = 0.f;
    #pragma unroll 8
    for (int c = 0; c < CFE; ++c) { float v = p[c * NPIX]; a = fmaf(v, v, a); }
    const float* q = sm + (size_t)b * CMA * NPIX + m;
    float am = 0.f;
    #pragma unroll
    for (int c = 0; c < CMA; ++c) { float v = q[c * NPIX]; am = fmaf(v, v, am); }
    psf[g] = a; psm[g] = am;
}

// 9-tap masked patch-norms -> combined reciprocal rn2 = 1/(||f||*||m||)
__global__ __launch_bounds__(256)
void rn2_kernel(const float* __restrict__ psf, const float* __restrict__ psm,
                float* __restrict__ rn2) {
    int g = blockIdx.x * 256 + threadIdx.x;
    if (g >= 2 * NPIX) return;
    int b = g / NPIX, m = g - b * NPIX;
    int mh = m / WW, mw = m - mh * WW;
    float sF = 0.f, sM = 0.f;
    #pragma unroll
    for (int di = -1; di <= 1; ++di) {
        if ((unsigned)(mh + di) >= HH) continue;
        #pragma unroll
        for (int dj = -1; dj <= 1; ++dj) {
            if ((unsigned)(mw + dj) >= WW) continue;
            int mm = m + di * WW + dj;
            sF += psf[b * NPIX + mm];
            sM += psm[b * NPIX + mm];
        }
    }
    float rf = 1.f / fmaxf(sqrtf(sF), 1e-12f);
    float rm = 1.f / fmaxf(sqrtf(sM), 1e-12f);
    rn2[g] = rf * rm;
}

// ---------------------------------------------------------------------------
// Build zero-padded 82x82 copies of all four inputs (borders pre-zeroed by
// the memset in kernel_launch; this writes the interior).
// ---------------------------------------------------------------------------
__global__ __launch_bounds__(256)
void pad_kernel(const float* __restrict__ cf, const float* __restrict__ sf,
                const float* __restrict__ cm, const float* __restrict__ sm,
                float* __restrict__ cfp, float* __restrict__ sfp,
                float* __restrict__ cmp, float* __restrict__ smp) {
    int gid = blockIdx.x * 256 + threadIdx.x;
    if (gid >= 2 * 2 * 67 * NPIX) return;
    int pix = gid % NPIX; int t = gid / NPIX;
    int c = t % 67; t /= 67;
    int b = t & 1; int which = t >> 1;
    int h = pix / WW, w = pix - h * WW;
    int qq = (h + 1) * PW + (w + 1);
    if (which == 0) {
        if (c < 64) cfp[((size_t)b * CFE + c) * NPP + qq] = cf[((size_t)b * CFE + c) * NPIX + pix];
        else        cmp[((size_t)b * CMA + (c - 64)) * NPP + qq] = cm[((size_t)b * CMA + (c - 64)) * NPIX + pix];
    } else {
        if (c < 64) sfp[((size_t)b * CFE + c) * NPP + qq] = sf[((size_t)b * CFE + c) * NPIX + pix];
        else        smp[((size_t)b * CMA + (c - 64)) * NPP + qq] = sm[((size_t)b * CMA + (c - 64)) * NPIX + pix];
    }
}

// ---------------------------------------------------------------------------
// Fused: correlation GEMM (diagonal coords) + maskless 9-tap stencil + score
// + argmax, all in one block. No S0 materialization in global memory.
// Block: 600 output rows (p), 32 diagonals (d). Pext = 768 rows incl. halo.
// ---------------------------------------------------------------------------
__global__ __launch_bounds__(256, 1)
void fuse_kernel(const float* __restrict__ cfp, const float* __restrict__ sfp,
                 const float* __restrict__ cmp, const float* __restrict__ smp,
                 const float* __restrict__ rn2, u64* __restrict__ pbest) {
    const int dt = blockIdx.x;
    const int pt = blockIdx.y;
    const int b  = blockIdx.z;
    const int pstart = 83 + 600 * pt;
    const int pend   = min(pstart + 600, 6641);
    const int pbase  = pstart - 84;
    const int d0     = -6560 + 32 * dt;
    if (pend - 1 + d0 + 31 < 83 || pstart + d0 > 6640) return;

    __shared__ float pool[27648];   // max(2x12544 staging, 768x36 S0 buffer)

    const int tid = threadIdx.x;
    const int tp = tid & 63, tg = tid >> 6;
    const int wb = tid & 192;       // wave-uniform LDS base part

    const float* cfb = cfp + (size_t)b * CFE * NPP + pbase;
    const float* sfb = sfp + (size_t)b * CFE * NPP + pbase + d0;
    const float* cmb = cmp + (size_t)b * CMA * NPP + pbase;
    const float* smb = smp + (size_t)b * CMA * NPP + pbase + d0;

    float acc[3][4][8];
    float pdF[3][32], pdM[3][32];

    auto zacc = [&]() {
        #pragma unroll
        for (int s = 0; s < 3; ++s)
            #pragma unroll
            for (int k = 0; k < 4; ++k)
                #pragma unroll
                for (int j = 0; j < 8; ++j) acc[s][k][j] = 0.f;
    };

    // stage one 8-channel chunk (A rows 768, B rows 800) into buf
    auto stageF = [&](int q, int buf) {
        float* Ab = pool + buf * 12544;
        float* Bb = Ab + 6144;
        const float* As = cfb + (size_t)(q * 8) * NPP;
        const float* Bs = sfb + (size_t)(q * 8) * NPP;
        #pragma unroll
        for (int cc = 0; cc < 8; ++cc) {
            #pragma unroll
            for (int k = 0; k < 3; ++k)
                gload4(As + cc * NPP + tid + 256 * k, Ab + cc * 768 + 256 * k + wb);
            #pragma unroll
            for (int k = 0; k < 3; ++k)
                gload4(Bs + cc * NPP + tid + 256 * k, Bb + cc * 800 + 256 * k + wb);
            if (tid < 32) gload4(Bs + cc * NPP + 768 + tid, Bb + cc * 800 + 768);
        }
    };

    // one channel of correlation: acc[s][k][j] += A[x]*B[x+dl]
    auto gemmc = [&](const float* Ab, const float* Bb) {
        const float* Ar = Ab + 4 * tp;
        const float* Br = Bb + 4 * tp + 8 * tg;
        #pragma unroll
        for (int s = 0; s < 3; ++s) {
            float a[4], bb[12];
            *(float4*)a        = ld4(Ar + 256 * s);
            *(float4*)bb       = ld4(Br + 256 * s);
            *(float4*)(bb + 4) = ld4(Br + 256 * s + 4);
            *(float4*)(bb + 8) = ld4(Br + 256 * s + 8);
            #pragma unroll
            for (int k = 0; k < 4; ++k)
                #pragma unroll
                for (int j = 0; j < 8; ++j)
                    acc[s][k][j] = fmaf(a[k], bb[k + j], acc[s][k][j]);
        }
    };

    // write acc -> S0 LDS buffer [768 rows][32 d], row stride 36
    auto s0write = [&]() {
        #pragma unroll
        for (int s = 0; s < 3; ++s)
            #pragma unroll
            for (int k = 0; k < 4; ++k) {
                float* d = pool + (4 * tp + 256 * s + k) * 36 + 8 * tg;
                *(float4*)d       = make_float4(acc[s][k][0], acc[s][k][1], acc[s][k][2], acc[s][k][3]);
                *(float4*)(d + 4) = make_float4(acc[s][k][4], acc[s][k][5], acc[s][k][6], acc[s][k][7]);
            }
    };

    // maskless 9-tap stencil along p; thread owns rows {tid, tid+256, tid+512}
    auto tapsrun = [&](float (&pd)[3][32]) {
        #pragma unroll
        for (int s2 = 0; s2 < 3; ++s2) {
            int row = tid + 256 * s2;
            if (row < 84 || row >= 684) continue;
            const float* Lr = pool + row * 36;
            #pragma unroll
            for (int j4 = 0; j4 < 8; ++j4) {
                float4 v = ld4(Lr - 83 * 36 + 4 * j4);
                float4 t;
                t = ld4(Lr - 82 * 36 + 4 * j4); v.x += t.x; v.y += t.y; v.z += t.z; v.w += t.w;
                t = ld4(Lr - 81 * 36 + 4 * j4); v.x += t.x; v.y += t.y; v.z += t.z; v.w += t.w;
                t = ld4(Lr -      36 + 4 * j4); v.x += t.x; v.y += t.y; v.z += t.z; v.w += t.w;
                t = ld4(Lr           + 4 * j4); v.x += t.x; v.y += t.y; v.z += t.z; v.w += t.w;
                t = ld4(Lr +      36 + 4 * j4); v.x += t.x; v.y += t.y; v.z += t.z; v.w += t.w;
                t = ld4(Lr + 81 * 36 + 4 * j4); v.x += t.x; v.y += t.y; v.z += t.z; v.w += t.w;
                t = ld4(Lr + 82 * 36 + 4 * j4); v.x += t.x; v.y += t.y; v.z += t.z; v.w += t.w;
                t = ld4(Lr + 83 * 36 + 4 * j4); v.x += t.x; v.y += t.y; v.z += t.z; v.w += t.w;
                pd[s2][j4 * 4 + 0] = v.x; pd[s2][j4 * 4 + 1] = v.y;
                pd[s2][j4 * 4 + 2] = v.z; pd[s2][j4 * 4 + 3] = v.w;
            }
        }
    };

    // ---- feature correlation: 8 chunks of 8 channels, double-buffered
    zacc();
    stageF(0, 0);
    __syncthreads();
    int buf = 0;
    #pragma unroll 1
    for (int q = 0; q < 8; ++q) {
        if (q < 7) stageF(q + 1, buf ^ 1);
        const float* Ab = pool + buf * 12544;
        #pragma unroll 2
        for (int cc = 0; cc < 8; ++cc)
            gemmc(Ab + cc * 768, Ab + 6144 + cc * 800);
        __syncthreads();
        buf ^= 1;
    }
    s0write();
    __syncthreads();
    tapsrun(pdF);
    __syncthreads();

    // ---- mask correlation: 3 channels, single stage
    #pragma unroll
    for (int cc = 0; cc < 3; ++cc) {
        #pragma unroll
        for (int k = 0; k < 3; ++k)
            gload4(cmb + cc * NPP + tid + 256 * k, pool + cc * 768 + 256 * k + wb);
        #pragma unroll
        for (int k = 0; k < 3; ++k)
            gload4(smb + cc * NPP + tid + 256 * k, pool + 2304 + cc * 800 + 256 * k + wb);
        if (tid < 32) gload4(smb + cc * NPP + 768 + tid, pool + 2304 + cc * 800 + 768);
    }
    __syncthreads();
    zacc();
    #pragma unroll
    for (int cc = 0; cc < 3; ++cc)
        gemmc(pool + cc * 768, pool + 2304 + cc * 800);
    __syncthreads();
    s0write();
    __syncthreads();
    tapsrun(pdM);

    // ---- score + argmax (read-filtered atomicMax of sortable key)
    const float* rb = rn2 + b * NPIX;
    u64* pb = pbest + ((size_t)(dt & (NREG - 1)) * 2 + b) * NPIX;
    #pragma unroll
    for (int s2 = 0; s2 < 3; ++s2) {
        int row = tid + 256 * s2;
        if (row < 84 || row >= 684) continue;
        int p = pbase + row;
        if (p >= pend) continue;
        int ph = p / PW, pw2 = p - ph * PW;
        if (ph < 1 || ph > 80 || pw2 < 1 || pw2 > 80) continue;
        int n_real = (ph - 1) * 80 + (pw2 - 1);
        u64 key = 0;
        #pragma unroll
        for (int j = 0; j < 32; ++j) {
            int m = p + d0 + j;
            if (m < 83 || m > 6640) continue;
            int mh = m / PW, mw = m - mh * PW;
            if (mw < 1 || mw > 80) continue;
            int mr = (mh - 1) * 80 + (mw - 1);
            float sc = pdF[s2][j] * pdM[s2][j] * rb[mr];
            sc += 0.f;                                  // -0 -> +0
            u32 u = __float_as_uint(sc);
            u ^= (u >> 31) ? 0xFFFFFFFFu : 0x80000000u;
            u64 k2 = ((u64)u << 32) | (u32)~(u32)mr;
            if (k2 > key) key = k2;
        }
        if (key) {
            u64 cur = pb[n_real];                       // monotone -> safe filter
            if (key > cur) atomicMax(&pb[n_real], key);
        }
    }
}

// ---------------------------------------------------------------------------
// Reduce the NREG region keys + gather the winning style patch per n.
// ---------------------------------------------------------------------------
__global__ __launch_bounds__(64)
void gather_kernel(const float* __restrict__ sf, const u64* __restrict__ pbest,
                   float* __restrict__ out) {
    int n = blockIdx.x, b = blockIdx.y;
    int lane = threadIdx.x;

    u64 key = 0;
    #pragma unroll
    for (int r = 0; r < NREG; ++r) {
        u64 k = pbest[((size_t)r * 2 + b) * NPIX + n];
        if (k > key) key = k;
    }
    int m = (int)(~(u32)key);
    if ((unsigned)m >= NPIX) m = 0;
    int mh = m / WW, mw = m - mh * WW;
    const float* sfb = sf + (size_t)b * CFE * NPIX;
    float* ob = out + ((size_t)b * NPIX + n) * (size_t)KF;
    #pragma unroll
    for (int e = lane; e < KF; e += 64) {
        int c = e / 9, pos = e - c * 9;
        int di = pos / 3 - 1, dj = pos - (pos / 3) * 3 - 1;
        int h = mh + di, w = mw + dj;
        ob[e] = ((unsigned)h < HH && (unsigned)w < WW) ? sfb[c * NPIX + h * WW + w] : 0.f;
    }
}

// ---------------------------------------------------------------------------
extern "C" void kernel_launch(void* const* d_in, const int* in_sizes, int n_in,
                              void* d_out, int out_size, void* d_ws, size_t ws_size,
                              hipStream_t stream) {
    const float* cf = (const float*)d_in[0];
    const float* sf = (const float*)d_in[1];
    const float* cm = (const float*)d_in[2];
    const float* sm = (const float*)d_in[3];
    float* out = (float*)d_out;

    // ws layout (floats)
    float* psf = (float*)d_ws;                  // 12800
    float* psm = psf + 2 * NPIX;                // 12800
    float* rn2 = psm + 2 * NPIX;                // 12800
    u64*  pbest = (u64*)(rn2 + 2 * NPIX);       // NREG*2*6400 u64
    float* padreg = (float*)(pbest + (size_t)NREG * 2 * NPIX);
    float* cfp = padreg + GUARD;                             // 2*64*NPP
    float* sfp = cfp + (size_t)2 * CFE * NPP + GUARD;        // 2*64*NPP
    float* cmp = sfp + (size_t)2 * CFE * NPP + GUARD;        // 2*3*NPP
    float* smp = cmp + (size_t)2 * CMA * NPP + GUARD;        // 2*3*NPP

    // zero pbest + entire padded region (guards + pad borders) in one shot
    size_t zero_bytes = (size_t)NREG * 2 * NPIX * 8 +
        ((size_t)5 * GUARD + 2 * ((size_t)2 * CFE * NPP) + 2 * ((size_t)2 * CMA * NPP)) * 4;
    hipMemsetAsync(pbest, 0, zero_bytes, stream);

    pad_kernel<<<(2 * 2 * 67 * NPIX + 255) / 256, 256, 0, stream>>>(
        cf, sf, cm, sm, cfp, sfp, cmp, smp);
    pixsq_kernel<<<(2 * NPIX + 255) / 256, 256, 0, stream>>>(sf, sm, psf, psm);
    rn2_kernel  <<<(2 * NPIX + 255) / 256, 256, 0, stream>>>(psf, psm, rn2);

    fuse_kernel<<<dim3(410, 11, 2), 256, 0, stream>>>(cfp, sfp, cmp, smp, rn2, pbest);

    gather_kernel<<<dim3(NPIX, 2), 64, 0, stream>>>(sf, pbest, out);
}

// Round 7
// 620.266 us; speedup vs baseline: 9.1452x; 1.6010x over previous
//
#include <hip/hip_runtime.h>

#define HH 80
#define WW 80
#define NPIX 6400
#define PW 82
#define NPP (PW*PW)        // 6724 padded pixels
#define CFE 64
#define CMA 3
#define KF 576
#define GUARD 1024
#define NREG 8

#define PA 1024            // S0 row window per block (incl. 84+84 halo)
#define POUT 856           // output rows per block
#define BW 1056            // B row window = PA + 32

typedef unsigned long long u64;
typedef unsigned int u32;

__device__ __forceinline__ void gload4(const float* g, float* l) {
    __builtin_amdgcn_global_load_lds((const __attribute__((address_space(1))) void*)g,
                                     (__attribute__((address_space(3))) void*)l, 4, 0, 0);
}
__device__ __forceinline__ float4 ld4(const float* p) { return *(const float4*)p; }

// ---------------------------------------------------------------------------
// per-pixel channel sum-of-squares (style side only), real grid
// ---------------------------------------------------------------------------
__global__ __launch_bounds__(256)
void pixsq_kernel(const float* __restrict__ sf, const float* __restrict__ sm,
                  float* __restrict__ psf, float* __restrict__ psm) {
    int g = blockIdx.x * 256 + threadIdx.x;
    if (g >= 2 * NPIX) return;
    int b = g / NPIX, m = g - b * NPIX;
    const float* p = sf + (size_t)b * CFE * NPIX + m;
    float a = 0.f;
    #pragma unroll 8
    for (int c = 0; c < CFE; ++c) { float v = p[c * NPIX]; a = fmaf(v, v, a); }
    const float* q = sm + (size_t)b * CMA * NPIX + m;
    float am = 0.f;
    #pragma unroll
    for (int c = 0; c < CMA; ++c) { float v = q[c * NPIX]; am = fmaf(v, v, am); }
    psf[g] = a; psm[g] = am;
}

// 9-tap masked patch-norms -> combined reciprocal rn2 = 1/(||f||*||m||)
__global__ __launch_bounds__(256)
void rn2_kernel(const float* __restrict__ psf, const float* __restrict__ psm,
                float* __restrict__ rn2) {
    int g = blockIdx.x * 256 + threadIdx.x;
    if (g >= 2 * NPIX) return;
    int b = g / NPIX, m = g - b * NPIX;
    int mh = m / WW, mw = m - mh * WW;
    float sF = 0.f, sM = 0.f;
    #pragma unroll
    for (int di = -1; di <= 1; ++di) {
        if ((unsigned)(mh + di) >= HH) continue;
        #pragma unroll
        for (int dj = -1; dj <= 1; ++dj) {
            if ((unsigned)(mw + dj) >= WW) continue;
            int mm = m + di * WW + dj;
            sF += psf[b * NPIX + mm];
            sM += psm[b * NPIX + mm];
        }
    }
    float rf = 1.f / fmaxf(sqrtf(sF), 1e-12f);
    float rm = 1.f / fmaxf(sqrtf(sM), 1e-12f);
    rn2[g] = rf * rm;
}

// ---------------------------------------------------------------------------
// Build zero-padded 82x82 copies (borders pre-zeroed by the memset).
// ---------------------------------------------------------------------------
__global__ __launch_bounds__(256)
void pad_kernel(const float* __restrict__ cf, const float* __restrict__ sf,
                const float* __restrict__ cm, const float* __restrict__ sm,
                float* __restrict__ cfp, float* __restrict__ sfp,
                float* __restrict__ cmp, float* __restrict__ smp) {
    int gid = blockIdx.x * 256 + threadIdx.x;
    if (gid >= 2 * 2 * 67 * NPIX) return;
    int pix = gid % NPIX; int t = gid / NPIX;
    int c = t % 67; t /= 67;
    int b = t & 1; int which = t >> 1;
    int h = pix / WW, w = pix - h * WW;
    int qq = (h + 1) * PW + (w + 1);
    if (which == 0) {
        if (c < 64) cfp[((size_t)b * CFE + c) * NPP + qq] = cf[((size_t)b * CFE + c) * NPIX + pix];
        else        cmp[((size_t)b * CMA + (c - 64)) * NPP + qq] = cm[((size_t)b * CMA + (c - 64)) * NPIX + pix];
    } else {
        if (c < 64) sfp[((size_t)b * CFE + c) * NPP + qq] = sf[((size_t)b * CFE + c) * NPIX + pix];
        else        smp[((size_t)b * CMA + (c - 64)) * NPP + qq] = sm[((size_t)b * CMA + (c - 64)) * NPIX + pix];
    }
}

// ---------------------------------------------------------------------------
// Fused: correlation GEMM (diagonal coords) + maskless 9-tap stencil + score
// + argmax. 1024 threads, 1024-row window x 32 diagonals, 16 waves/CU.
// ---------------------------------------------------------------------------
__global__ __launch_bounds__(1024, 4)
void fuse_kernel(const float* __restrict__ cfp, const float* __restrict__ sfp,
                 const float* __restrict__ cmp, const float* __restrict__ smp,
                 const float* __restrict__ rn2, u64* __restrict__ pbest) {
    const int dt = blockIdx.x;
    const int pt = blockIdx.y;
    const int b  = blockIdx.z;
    const int pstart = 83 + POUT * pt;
    const int pend   = min(pstart + POUT, 6641);
    const int pbase  = pstart - 84;
    const int d0     = -6560 + 32 * dt;
    if (pend - 1 + d0 + 31 < 83 || pstart + d0 > 6640) return;

    __shared__ float pool[PA * 36];          // 147456 B; staging aliases (2x16640 fl)

    const int tid = threadIdx.x;
    const int tp = tid & 255;                // 4 rows each
    const int tg = tid >> 8;                 // 8 diagonals each
    const int wb = tid & 960;                // wave-uniform LDS float offset

    const float* cfb = cfp + (size_t)b * CFE * NPP + pbase;
    const float* sfb = sfp + (size_t)b * CFE * NPP + pbase + d0;
    const float* cmb = cmp + (size_t)b * CMA * NPP + pbase;
    const float* smb = smp + (size_t)b * CMA * NPP + pbase + d0;

    float acc[4][8];
    float pdF[32], pdM[32];

    auto zacc = [&]() {
        #pragma unroll
        for (int k = 0; k < 4; ++k)
            #pragma unroll
            for (int j = 0; j < 8; ++j) acc[k][j] = 0.f;
    };

    // stage one 8-channel chunk: A rows PA, B rows BW
    auto stageF = [&](int q, int buf) {
        float* Ab = pool + buf * 16640;
        float* Bb = Ab + 8 * PA;
        const float* As = cfb + (size_t)(q * 8) * NPP;
        const float* Bs = sfb + (size_t)(q * 8) * NPP;
        #pragma unroll
        for (int cc = 0; cc < 8; ++cc) {
            gload4(As + cc * NPP + tid, Ab + cc * PA + wb);
            gload4(Bs + cc * NPP + tid, Bb + cc * BW + wb);
            if (tid < 32) gload4(Bs + cc * NPP + 1024 + tid, Bb + cc * BW + 1024);
        }
    };

    // one channel: acc[k][j] += A[4tp+k] * B[4tp+k + 8tg+j]
    auto gemmc = [&](const float* Ab, const float* Bb) {
        const float* Ar = Ab + 4 * tp;
        const float* Br = Bb + 4 * tp + 8 * tg;
        float a[4], bb[12];
        *(float4*)a        = ld4(Ar);
        *(float4*)bb       = ld4(Br);
        *(float4*)(bb + 4) = ld4(Br + 4);
        *(float4*)(bb + 8) = ld4(Br + 8);
        #pragma unroll
        for (int k = 0; k < 4; ++k)
            #pragma unroll
            for (int j = 0; j < 8; ++j)
                acc[k][j] = fmaf(a[k], bb[k + j], acc[k][j]);
    };

    // acc -> S0 LDS [PA rows][32 d], row stride 36
    auto s0write = [&]() {
        #pragma unroll
        for (int k = 0; k < 4; ++k) {
            float* d = pool + (4 * tp + k) * 36 + 8 * tg;
            *(float4*)d       = make_float4(acc[k][0], acc[k][1], acc[k][2], acc[k][3]);
            *(float4*)(d + 4) = make_float4(acc[k][4], acc[k][5], acc[k][6], acc[k][7]);
        }
    };

    // maskless 9-tap stencil along p; thread owns row tid
    auto tapsrun = [&](float (&pd)[32]) {
        const int row = tid;
        if (row < 84 || row >= 84 + POUT) return;
        const float* Lr = pool + row * 36;
        #pragma unroll
        for (int j4 = 0; j4 < 8; ++j4) {
            float4 v = ld4(Lr - 83 * 36 + 4 * j4);
            float4 t;
            t = ld4(Lr - 82 * 36 + 4 * j4); v.x += t.x; v.y += t.y; v.z += t.z; v.w += t.w;
            t = ld4(Lr - 81 * 36 + 4 * j4); v.x += t.x; v.y += t.y; v.z += t.z; v.w += t.w;
            t = ld4(Lr -      36 + 4 * j4); v.x += t.x; v.y += t.y; v.z += t.z; v.w += t.w;
            t = ld4(Lr           + 4 * j4); v.x += t.x; v.y += t.y; v.z += t.z; v.w += t.w;
            t = ld4(Lr +      36 + 4 * j4); v.x += t.x; v.y += t.y; v.z += t.z; v.w += t.w;
            t = ld4(Lr + 81 * 36 + 4 * j4); v.x += t.x; v.y += t.y; v.z += t.z; v.w += t.w;
            t = ld4(Lr + 82 * 36 + 4 * j4); v.x += t.x; v.y += t.y; v.z += t.z; v.w += t.w;
            t = ld4(Lr + 83 * 36 + 4 * j4); v.x += t.x; v.y += t.y; v.z += t.z; v.w += t.w;
            pd[j4 * 4 + 0] = v.x; pd[j4 * 4 + 1] = v.y;
            pd[j4 * 4 + 2] = v.z; pd[j4 * 4 + 3] = v.w;
        }
    };

    // ---- feature correlation: 8 chunks of 8 channels, double-buffered
    zacc();
    stageF(0, 0);
    __syncthreads();
    int buf = 0;
    #pragma unroll 1
    for (int q = 0; q < 8; ++q) {
        if (q < 7) stageF(q + 1, buf ^ 1);
        const float* Ab = pool + buf * 16640;
        const float* Bb = Ab + 8 * PA;
        #pragma unroll 2
        for (int cc = 0; cc < 8; ++cc)
            gemmc(Ab + cc * PA, Bb + cc * BW);
        __syncthreads();
        buf ^= 1;
    }
    s0write();
    __syncthreads();
    tapsrun(pdF);
    __syncthreads();

    // ---- mask correlation: 3 channels, single stage
    #pragma unroll
    for (int cc = 0; cc < 3; ++cc) {
        gload4(cmb + cc * NPP + tid, pool + cc * PA + wb);
        gload4(smb + cc * NPP + tid, pool + 3 * PA + cc * BW + wb);
        if (tid < 32) gload4(smb + cc * NPP + 1024 + tid, pool + 3 * PA + cc * BW + 1024);
    }
    __syncthreads();
    zacc();
    #pragma unroll
    for (int cc = 0; cc < 3; ++cc)
        gemmc(pool + cc * PA, pool + 3 * PA + cc * BW);
    __syncthreads();
    s0write();
    __syncthreads();
    tapsrun(pdM);

    // ---- score + argmax (read-filtered atomicMax of sortable key)
    const float* rb = rn2 + b * NPIX;
    u64* pb = pbest + ((size_t)(dt & (NREG - 1)) * 2 + b) * NPIX;
    {
        const int row = tid;
        const int p = pbase + row;
        if (row >= 84 && p < pend) {
            int ph = p / PW, pw2 = p - ph * PW;
            if (ph >= 1 && ph <= 80 && pw2 >= 1 && pw2 <= 80) {
                int n_real = (ph - 1) * 80 + (pw2 - 1);
                u64 key = 0;
                #pragma unroll
                for (int j = 0; j < 32; ++j) {
                    int m = p + d0 + j;
                    if (m < 83 || m > 6640) continue;
                    int mh = m / PW, mw = m - mh * PW;
                    if (mw < 1 || mw > 80) continue;
                    int mr = (mh - 1) * 80 + (mw - 1);
                    float sc = pdF[j] * pdM[j] * rb[mr];
                    sc += 0.f;                                  // -0 -> +0
                    u32 u = __float_as_uint(sc);
                    u ^= (u >> 31) ? 0xFFFFFFFFu : 0x80000000u;
                    u64 k2 = ((u64)u << 32) | (u32)~(u32)mr;
                    if (k2 > key) key = k2;
                }
                if (key) {
                    u64 cur = pb[n_real];                       // monotone -> safe filter
                    if (key > cur) atomicMax(&pb[n_real], key);
                }
            }
        }
    }
}

// ---------------------------------------------------------------------------
// Reduce the NREG region keys + gather the winning style patch per n.
// ---------------------------------------------------------------------------
__global__ __launch_bounds__(64)
void gather_kernel(const float* __restrict__ sf, const u64* __restrict__ pbest,
                   float* __restrict__ out) {
    int n = blockIdx.x, b = blockIdx.y;
    int lane = threadIdx.x;

    u64 key = 0;
    #pragma unroll
    for (int r = 0; r < NREG; ++r) {
        u64 k = pbest[((size_t)r * 2 + b) * NPIX + n];
        if (k > key) key = k;
    }
    int m = (int)(~(u32)key);
    if ((unsigned)m >= NPIX) m = 0;
    int mh = m / WW, mw = m - mh * WW;
    const float* sfb = sf + (size_t)b * CFE * NPIX;
    float* ob = out + ((size_t)b * NPIX + n) * (size_t)KF;
    #pragma unroll
    for (int e = lane; e < KF; e += 64) {
        int c = e / 9, pos = e - c * 9;
        int di = pos / 3 - 1, dj = pos - (pos / 3) * 3 - 1;
        int h = mh + di, w = mw + dj;
        ob[e] = ((unsigned)h < HH && (unsigned)w < WW) ? sfb[c * NPIX + h * WW + w] : 0.f;
    }
}

// ---------------------------------------------------------------------------
extern "C" void kernel_launch(void* const* d_in, const int* in_sizes, int n_in,
                              void* d_out, int out_size, void* d_ws, size_t ws_size,
                              hipStream_t stream) {
    const float* cf = (const float*)d_in[0];
    const float* sf = (const float*)d_in[1];
    const float* cm = (const float*)d_in[2];
    const float* sm = (const float*)d_in[3];
    float* out = (float*)d_out;

    // ws layout (floats)
    float* psf = (float*)d_ws;                  // 12800
    float* psm = psf + 2 * NPIX;                // 12800
    float* rn2 = psm + 2 * NPIX;                // 12800
    u64*  pbest = (u64*)(rn2 + 2 * NPIX);       // NREG*2*6400 u64
    float* padreg = (float*)(pbest + (size_t)NREG * 2 * NPIX);
    float* cfp = padreg + GUARD;                             // 2*64*NPP
    float* sfp = cfp + (size_t)2 * CFE * NPP + GUARD;        // 2*64*NPP
    float* cmp = sfp + (size_t)2 * CFE * NPP + GUARD;        // 2*3*NPP
    float* smp = cmp + (size_t)2 * CMA * NPP + GUARD;        // 2*3*NPP

    // zero pbest + entire padded region (guards + pad borders) in one shot
    size_t zero_bytes = (size_t)NREG * 2 * NPIX * 8 +
        ((size_t)5 * GUARD + 2 * ((size_t)2 * CFE * NPP) + 2 * ((size_t)2 * CMA * NPP)) * 4;
    hipMemsetAsync(pbest, 0, zero_bytes, stream);

    pad_kernel<<<(2 * 2 * 67 * NPIX + 255) / 256, 256, 0, stream>>>(
        cf, sf, cm, sm, cfp, sfp, cmp, smp);
    pixsq_kernel<<<(2 * NPIX + 255) / 256, 256, 0, stream>>>(sf, sm, psf, psm);
    rn2_kernel  <<<(2 * NPIX + 255) / 256, 256, 0, stream>>>(psf, psm, rn2);

    fuse_kernel<<<dim3(410, 8, 2), 1024, 0, stream>>>(cfp, sfp, cmp, smp, rn2, pbest);

    gather_kernel<<<dim3(NPIX, 2), 64, 0, stream>>>(sf, pbest, out);
}